// Round 1
// baseline (277.644 us; speedup 1.0000x reference)
//
#include <hip/hip_runtime.h>
#include <hip/hip_bf16.h>

#define NPTS 200000
#define NVOX 60000
#define NB 4
#define KK 27

// ---- mask encoding: 0 = uint8 bool, 1 = int32, 2 = float32 ----
__device__ __forceinline__ float get_mask(const void* nm, int fl, long i) {
    if (fl == 0) return ((const unsigned char*)nm)[i] ? 1.0f : 0.0f;
    if (fl == 1) return ((const int*)nm)[i] ? 1.0f : 0.0f;
    return ((const float*)nm)[i];
}

__global__ void k_detect(const unsigned int* nm, int* flag) {
    __shared__ int cntF, cntI;
    if (threadIdx.x == 0) { cntF = 0; cntI = 0; }
    __syncthreads();
    int f = 0, i1 = 0;
    for (int i = threadIdx.x; i < 1024; i += 256) {
        unsigned int v = nm[i];          // first 4096 bytes — safe for all encodings
        if (v == 0x3f800000u) f++;
        if (v == 1u) i1++;
    }
    atomicAdd(&cntF, f); atomicAdd(&cntI, i1);
    __syncthreads();
    if (threadIdx.x == 0)
        *flag = (cntF > 100) ? 2 : ((cntI > 100) ? 1 : 0);
}

// ---- voxelize: scatter-add points into voxels ----
__global__ void k_scatter(const float4* __restrict__ feat, const int* __restrict__ p2v,
                          float* cnt, float* vox) {
    int p = blockIdx.x * 256 + threadIdx.x;
    if (p >= NPTS) return;
    int v = p2v[p];
    float4 f = feat[p];
    atomicAdd(&cnt[v], 1.0f);
    atomicAdd(&vox[v * 4 + 0], f.x);
    atomicAdd(&vox[v * 4 + 1], f.y);
    atomicAdd(&vox[v * 4 + 2], f.z);
    atomicAdd(&vox[v * 4 + 3], f.w);
}

__global__ void k_voxdiv(float* vox, const float* __restrict__ cnt) {
    int n = blockIdx.x * 256 + threadIdx.x;
    if (n >= NVOX) return;
    float inv = 1.0f / fmaxf(cnt[n], 1.0f);
    float4* vp = (float4*)(vox + n * 4);
    float4 v = *vp;
    v.x *= inv; v.y *= inv; v.z *= inv; v.w *= inv;
    *vp = v;
}

// ---- conv1: Cin=4 -> Cout=32, thread per voxel, W1 in LDS ----
__global__ __launch_bounds__(256) void k_conv1(
        const float* __restrict__ vox, const float* __restrict__ W1,
        const float* __restrict__ g1, const float* __restrict__ b1,
        const int* __restrict__ nidx, const void* __restrict__ nmask,
        const int* __restrict__ flag, float* __restrict__ h1) {
    __shared__ float w[KK * 4 * 32];
    for (int i = threadIdx.x; i < KK * 4 * 32; i += 256) w[i] = W1[i];
    __syncthreads();
    int n = blockIdx.x * 256 + threadIdx.x;
    if (n >= NVOX) return;
    int fl = *flag;
    float acc[32];
#pragma unroll
    for (int d = 0; d < 32; d++) acc[d] = 0.0f;
    for (int k = 0; k < KK; k++) {
        int idx = nidx[k * NVOX + n];
        float m = get_mask(nmask, fl, (long)k * NVOX + n);
        if (m != 0.0f) {
            float4 gv = ((const float4*)vox)[idx];
            gv.x *= m; gv.y *= m; gv.z *= m; gv.w *= m;
            const float* wk = &w[k * 128];
#pragma unroll
            for (int d = 0; d < 32; d++)
                acc[d] += gv.x * wk[d] + gv.y * wk[32 + d] + gv.z * wk[64 + d] + gv.w * wk[96 + d];
        }
    }
#pragma unroll
    for (int d = 0; d < 32; d++) {
        float o = acc[d] * g1[d] + b1[d];
        h1[n * 32 + d] = fmaxf(o, 0.0f);
    }
}

// ---- conv2: Cin=32 -> Cout=32, block = 32 voxels x 32 channels ----
#define RSTR 40   // padded LDS row stride (16B-aligned rows, <=2-way bank alias)
__global__ __launch_bounds__(256) void k_conv2(
        const float* __restrict__ h1, const float* __restrict__ W2,
        const float* __restrict__ g2, const float* __restrict__ b2,
        const int* __restrict__ nidx, const void* __restrict__ nmask,
        const int* __restrict__ flag, float* __restrict__ h2) {
    __shared__ float rows[32 * RSTR];
    __shared__ float wk[32 * 32];
    __shared__ int   sidx[KK * 32];
    __shared__ float smask[KK * 32];
    int tid = threadIdx.x;
    int lv = tid >> 3;        // voxel within block (0..31)
    int dq = tid & 7;         // output-channel quad (d = dq*4..dq*4+3)
    int n0 = blockIdx.x * 32;
    int fl = *flag;
    // preload all neighbor idx/mask for the 32 voxels
    for (int i = tid; i < KK * 32; i += 256) {
        int k = i >> 5, r = i & 31;
        sidx[i]  = nidx[k * NVOX + n0 + r];
        smask[i] = get_mask(nmask, fl, (long)k * NVOX + n0 + r);
    }
    __syncthreads();
    float4 acc = make_float4(0.f, 0.f, 0.f, 0.f);
    for (int k = 0; k < KK; k++) {
        { // stage masked-gathered rows + W2[k]
            int idx = sidx[k * 32 + lv];
            float m = smask[k * 32 + lv];
            float4 rv = ((const float4*)(h1 + (long)idx * 32))[dq];
            rv.x *= m; rv.y *= m; rv.z *= m; rv.w *= m;
            *((float4*)&rows[lv * RSTR + dq * 4]) = rv;
            ((float4*)wk)[tid] = ((const float4*)W2)[k * 256 + tid];
        }
        __syncthreads();
#pragma unroll
        for (int c = 0; c < 32; c++) {
            float rv = rows[lv * RSTR + c];
            float4 wv = ((float4*)wk)[c * 8 + dq];
            acc.x += rv * wv.x; acc.y += rv * wv.y;
            acc.z += rv * wv.z; acc.w += rv * wv.w;
        }
        __syncthreads();
    }
    int n = n0 + lv;
    float4 g = ((const float4*)g2)[dq];
    float4 b = ((const float4*)b2)[dq];
    float4 o;
    o.x = fmaxf(acc.x * g.x + b.x, 0.f);
    o.y = fmaxf(acc.y * g.y + b.y, 0.f);
    o.z = fmaxf(acc.z * g.z + b.z, 0.f);
    o.w = fmaxf(acc.w * g.w + b.w, 0.f);
    ((float4*)(h2 + (long)n * 32))[dq] = o;
}

// ---- per-batch pooling (sum + max) with LDS accumulators ----
__global__ __launch_bounds__(256) void k_pool(
        const float* __restrict__ h2, const int* __restrict__ vb,
        float* bsum, unsigned int* bmax, float* bcnt) {
    __shared__ float ls[NB * 32];
    __shared__ unsigned int lm[NB * 32];
    __shared__ float lc[NB];
    for (int i = threadIdx.x; i < NB * 32; i += 256) { ls[i] = 0.f; lm[i] = 0u; }
    if (threadIdx.x < NB) lc[threadIdx.x] = 0.f;
    __syncthreads();
    for (int n = blockIdx.x * 256 + threadIdx.x; n < NVOX; n += gridDim.x * 256) {
        int b = vb[n];
        atomicAdd(&lc[b], 1.0f);
#pragma unroll
        for (int q = 0; q < 8; q++) {
            float4 v = ((const float4*)(h2 + (long)n * 32))[q];
            atomicAdd(&ls[b * 32 + q * 4 + 0], v.x);
            atomicAdd(&ls[b * 32 + q * 4 + 1], v.y);
            atomicAdd(&ls[b * 32 + q * 4 + 2], v.z);
            atomicAdd(&ls[b * 32 + q * 4 + 3], v.w);
            atomicMax(&lm[b * 32 + q * 4 + 0], __float_as_uint(v.x));  // h2 >= 0
            atomicMax(&lm[b * 32 + q * 4 + 1], __float_as_uint(v.y));
            atomicMax(&lm[b * 32 + q * 4 + 2], __float_as_uint(v.z));
            atomicMax(&lm[b * 32 + q * 4 + 3], __float_as_uint(v.w));
        }
    }
    __syncthreads();
    for (int i = threadIdx.x; i < NB * 32; i += 256) {
        atomicAdd(&bsum[i], ls[i]);
        atomicMax(&bmax[i], lm[i]);
    }
    if (threadIdx.x < NB) atomicAdd(&bcnt[threadIdx.x], lc[threadIdx.x]);
}

// ---- channel-attention MLP (tiny, 4 batches) ----
__global__ void k_ca(const float* __restrict__ bsum, const unsigned int* __restrict__ bmax,
                     const float* __restrict__ bcnt,
                     const float* __restrict__ w1, const float* __restrict__ b1,
                     const float* __restrict__ w2, const float* __restrict__ b2,
                     float* ca) {
    int b = threadIdx.x;
    if (b >= NB) return;
    float avg[32], mx[32], o[32];
    float inv = 1.0f / fmaxf(bcnt[b], 1.0f);
#pragma unroll
    for (int c = 0; c < 32; c++) {
        avg[c] = bsum[b * 32 + c] * inv;
        mx[c]  = __uint_as_float(bmax[b * 32 + c]);
        o[c] = 0.f;
    }
#pragma unroll
    for (int pass = 0; pass < 2; pass++) {
        float r[8];
#pragma unroll
        for (int j = 0; j < 8; j++) {
            float s = b1[j];
#pragma unroll
            for (int c = 0; c < 32; c++) s += (pass ? mx[c] : avg[c]) * w1[c * 8 + j];
            r[j] = fmaxf(s, 0.f);
        }
#pragma unroll
        for (int d = 0; d < 32; d++) {
            float s = b2[d];
#pragma unroll
            for (int j = 0; j < 8; j++) s += r[j] * w2[j * 32 + d];
            o[d] += s;
        }
    }
#pragma unroll
    for (int d = 0; d < 32; d++)
        ca[b * 32 + d] = 1.0f / (1.0f + expf(-o[d]));
}

// ---- apply channel attention (in place) + build s2 = [mean_c, max_c] ----
__global__ void k_apply(float* h2, const float* __restrict__ ca,
                        const int* __restrict__ vb, float* __restrict__ s2) {
    int n = blockIdx.x * 256 + threadIdx.x;
    if (n >= NVOX) return;
    int b = vb[n];
    float sum = 0.f, mx = 0.f;   // values >= 0
    float4* hp = (float4*)(h2 + (long)n * 32);
    const float4* cp = (const float4*)(ca + b * 32);
#pragma unroll
    for (int q = 0; q < 8; q++) {
        float4 h = hp[q]; float4 c = cp[q];
        h.x *= c.x; h.y *= c.y; h.z *= c.z; h.w *= c.w;
        hp[q] = h;
        sum += h.x + h.y + h.z + h.w;
        mx = fmaxf(mx, fmaxf(fmaxf(h.x, h.y), fmaxf(h.z, h.w)));
    }
    s2[n * 2 + 0] = sum * (1.0f / 32.0f);
    s2[n * 2 + 1] = mx;
}

// ---- spatial attention: 2-ch sparse conv -> sigmoid ----
__global__ void k_saconv(const float* __restrict__ s2, const float* __restrict__ saW,
                         const int* __restrict__ nidx, const void* __restrict__ nmask,
                         const int* __restrict__ flag, float* __restrict__ sa) {
    __shared__ float w[KK * 2];
    if (threadIdx.x < KK * 2) w[threadIdx.x] = saW[threadIdx.x];
    __syncthreads();
    int n = blockIdx.x * 256 + threadIdx.x;
    if (n >= NVOX) return;
    int fl = *flag;
    float acc = 0.f;
    for (int k = 0; k < KK; k++) {
        int idx = nidx[k * NVOX + n];
        float m = get_mask(nmask, fl, (long)k * NVOX + n);
        float2 s = ((const float2*)s2)[idx];
        acc += m * (s.x * w[k * 2] + s.y * w[k * 2 + 1]);
    }
    sa[n] = 1.0f / (1.0f + expf(-acc));
}

// ---- gather to points, apply sa, classifier ----
__global__ __launch_bounds__(256) void k_final(
        const float* __restrict__ h2, const float* __restrict__ sa,
        const int* __restrict__ p2v, const float* __restrict__ clsw,
        const float* __restrict__ clsb, float* __restrict__ out) {
    __shared__ float w[32 * 20];
    __shared__ float bb[20];
    for (int i = threadIdx.x; i < 640; i += 256) w[i] = clsw[i];
    if (threadIdx.x < 20) bb[threadIdx.x] = clsb[threadIdx.x];
    __syncthreads();
    int p = blockIdx.x * 256 + threadIdx.x;
    if (p >= NPTS) return;
    int v = p2v[p];
    float s = sa[v];
    float acc[20];
#pragma unroll
    for (int j = 0; j < 20; j++) acc[j] = bb[j];
    const float4* hp = (const float4*)(h2 + (long)v * 32);
#pragma unroll
    for (int q = 0; q < 8; q++) {
        float4 h = hp[q];
        float z0 = h.x * s, z1 = h.y * s, z2 = h.z * s, z3 = h.w * s;
#pragma unroll
        for (int j = 0; j < 20; j++)
            acc[j] += z0 * w[(q * 4 + 0) * 20 + j] + z1 * w[(q * 4 + 1) * 20 + j]
                    + z2 * w[(q * 4 + 2) * 20 + j] + z3 * w[(q * 4 + 3) * 20 + j];
    }
#pragma unroll
    for (int j = 0; j < 20; j++) out[(long)p * 20 + j] = acc[j];
}

extern "C" void kernel_launch(void* const* d_in, const int* in_sizes, int n_in,
                              void* d_out, int out_size, void* d_ws, size_t ws_size,
                              hipStream_t stream) {
    const float* feat = (const float*)d_in[0];
    const float* W1   = (const float*)d_in[1];
    const float* g1   = (const float*)d_in[2];
    const float* b1   = (const float*)d_in[3];
    const float* W2   = (const float*)d_in[4];
    const float* g2   = (const float*)d_in[5];
    const float* b2   = (const float*)d_in[6];
    const float* caw1 = (const float*)d_in[7];
    const float* cab1 = (const float*)d_in[8];
    const float* caw2 = (const float*)d_in[9];
    const float* cab2 = (const float*)d_in[10];
    const float* saW  = (const float*)d_in[11];
    const float* clsw = (const float*)d_in[12];
    const float* clsb = (const float*)d_in[13];
    const int* p2v    = (const int*)d_in[14];
    const int* vb     = (const int*)d_in[15];
    const int* nidx   = (const int*)d_in[16];
    const void* nmask = d_in[17];
    float* out = (float*)d_out;

    float* f = (float*)d_ws;
    int* flag   = (int*)d_ws;
    float* cnt  = f + 64;
    float* vox  = cnt + NVOX;
    float* h1   = vox + (size_t)NVOX * 4;
    float* h2   = h1  + (size_t)NVOX * 32;
    float* s2   = h2  + (size_t)NVOX * 32;
    float* sa   = s2  + (size_t)NVOX * 2;
    float* bsum = sa  + NVOX;
    unsigned int* bmax = (unsigned int*)(bsum + NB * 32);
    float* bcnt = (float*)(bmax + NB * 32);
    float* ca   = bcnt + NB;

    hipMemsetAsync(cnt, 0, (size_t)NVOX * 5 * sizeof(float), stream);
    hipMemsetAsync(bsum, 0, (NB * 32 * 2 + NB) * sizeof(float), stream);
    k_detect<<<1, 256, 0, stream>>>((const unsigned int*)nmask, flag);
    k_scatter<<<(NPTS + 255) / 256, 256, 0, stream>>>((const float4*)feat, p2v, cnt, vox);
    k_voxdiv<<<(NVOX + 255) / 256, 256, 0, stream>>>(vox, cnt);
    k_conv1<<<(NVOX + 255) / 256, 256, 0, stream>>>(vox, W1, g1, b1, nidx, nmask, flag, h1);
    k_conv2<<<NVOX / 32, 256, 0, stream>>>(h1, W2, g2, b2, nidx, nmask, flag, h2);
    k_pool<<<256, 256, 0, stream>>>(h2, vb, bsum, bmax, bcnt);
    k_ca<<<1, 64, 0, stream>>>(bsum, bmax, bcnt, caw1, cab1, caw2, cab2, ca);
    k_apply<<<(NVOX + 255) / 256, 256, 0, stream>>>(h2, ca, vb, s2);
    k_saconv<<<(NVOX + 255) / 256, 256, 0, stream>>>(s2, saW, nidx, nmask, flag, sa);
    k_final<<<(NPTS + 255) / 256, 256, 0, stream>>>(h2, sa, p2v, clsw, clsb, out);
}

// Round 2
// 269.111 us; speedup vs baseline: 1.0317x; 1.0317x over previous
//
#include <hip/hip_runtime.h>
#include <hip/hip_bf16.h>

#define NPTS 200000
#define NVOX 60000
#define NB 4
#define KK 27

// ---- mask encoding: 0 = uint8 bool, 1 = int32, 2 = float32 ----
__device__ __forceinline__ float get_mask(const void* nm, int fl, long i) {
    if (fl == 0) return ((const unsigned char*)nm)[i] ? 1.0f : 0.0f;
    if (fl == 1) return ((const int*)nm)[i] ? 1.0f : 0.0f;
    return ((const float*)nm)[i];
}

__global__ void k_detect(const unsigned int* nm, int* flag) {
    __shared__ int cntF, cntI;
    if (threadIdx.x == 0) { cntF = 0; cntI = 0; }
    __syncthreads();
    int f = 0, i1 = 0;
    for (int i = threadIdx.x; i < 1024; i += 256) {
        unsigned int v = nm[i];
        if (v == 0x3f800000u) f++;
        if (v == 1u) i1++;
    }
    atomicAdd(&cntF, f); atomicAdd(&cntI, i1);
    __syncthreads();
    if (threadIdx.x == 0)
        *flag = (cntF > 100) ? 2 : ((cntI > 100) ? 1 : 0);
}

// ---- voxelize: scatter-add points into voxels ----
__global__ void k_scatter(const float4* __restrict__ feat, const int* __restrict__ p2v,
                          float* cnt, float* vox) {
    int p = blockIdx.x * 256 + threadIdx.x;
    if (p >= NPTS) return;
    int v = p2v[p];
    float4 f = feat[p];
    atomicAdd(&cnt[v], 1.0f);
    atomicAdd(&vox[v * 4 + 0], f.x);
    atomicAdd(&vox[v * 4 + 1], f.y);
    atomicAdd(&vox[v * 4 + 2], f.z);
    atomicAdd(&vox[v * 4 + 3], f.w);
}

__global__ void k_voxdiv(float* vox, const float* __restrict__ cnt) {
    int n = blockIdx.x * 256 + threadIdx.x;
    if (n >= NVOX) return;
    float inv = 1.0f / fmaxf(cnt[n], 1.0f);
    float4* vp = (float4*)(vox + n * 4);
    float4 v = *vp;
    v.x *= inv; v.y *= inv; v.z *= inv; v.w *= inv;
    *vp = v;
}

// ---- conv1: Cin=4 -> Cout=32; thread = (voxel, d-half). W1 via wave-uniform s_load ----
__global__ __launch_bounds__(256) void k_conv1(
        const float* __restrict__ vox, const float* __restrict__ W1,
        const float* __restrict__ g1, const float* __restrict__ b1,
        const int* __restrict__ nidx, const void* __restrict__ nmask,
        const int* __restrict__ flag, float* __restrict__ h1) {
    int v = blockIdx.x * 128 + (threadIdx.x & 127);
    int half = __builtin_amdgcn_readfirstlane(threadIdx.x >> 7);  // wave-uniform
    if (v >= NVOX) return;
    int fl = *flag;
    const float* Wh = W1 + half * 16;
    float acc[16];
#pragma unroll
    for (int d = 0; d < 16; d++) acc[d] = 0.f;
    float4 a, b = make_float4(0.f, 0.f, 0.f, 0.f);
    float m, mn = 0.f;
    {
        int idx = nidx[v];
        m = get_mask(nmask, fl, v);
        a = ((const float4*)vox)[idx];
    }
#pragma unroll 1
    for (int k = 0; k < KK; k++) {
        if (k + 1 < KK) {
            int idxn = nidx[(k + 1) * NVOX + v];
            mn = get_mask(nmask, fl, (long)(k + 1) * NVOX + v);
            b = ((const float4*)vox)[idxn];
        }
        const float* wk = Wh + k * 128;
#pragma unroll
        for (int c = 0; c < 4; c++) {
            float rc = (c == 0 ? a.x : c == 1 ? a.y : c == 2 ? a.z : a.w) * m;
            const float* wc = wk + c * 32;
#pragma unroll
            for (int d = 0; d < 16; d++) acc[d] = fmaf(rc, wc[d], acc[d]);
        }
        a = b; m = mn;
    }
    const float* gp = g1 + half * 16;
    const float* bp = b1 + half * 16;
    float o[16];
#pragma unroll
    for (int d = 0; d < 16; d++) o[d] = fmaxf(acc[d] * gp[d] + bp[d], 0.f);
    float4* op = (float4*)(h1 + (size_t)v * 32 + half * 16);
#pragma unroll
    for (int q = 0; q < 4; q++)
        op[q] = make_float4(o[q * 4], o[q * 4 + 1], o[q * 4 + 2], o[q * 4 + 3]);
}

// ---- conv2: Cin=32 -> Cout=32; thread = (voxel, d-half), no LDS, no barriers ----
__global__ __launch_bounds__(256) void k_conv2(
        const float* __restrict__ h1, const float* __restrict__ W2,
        const float* __restrict__ g2, const float* __restrict__ b2,
        const int* __restrict__ nidx, const void* __restrict__ nmask,
        const int* __restrict__ flag, float* __restrict__ h2) {
    int v = blockIdx.x * 128 + (threadIdx.x & 127);
    int half = __builtin_amdgcn_readfirstlane(threadIdx.x >> 7);  // wave-uniform
    if (v >= NVOX) return;
    int fl = *flag;
    const float* Wh = W2 + half * 16;
    float acc[16];
#pragma unroll
    for (int d = 0; d < 16; d++) acc[d] = 0.f;
    float4 a[8], b[8];
#pragma unroll
    for (int q = 0; q < 8; q++) b[q] = make_float4(0.f, 0.f, 0.f, 0.f);
    float m, mn = 0.f;
    {
        int idx = nidx[v];
        m = get_mask(nmask, fl, v);
        const float4* rp = (const float4*)(h1 + (size_t)idx * 32);
#pragma unroll
        for (int q = 0; q < 8; q++) a[q] = rp[q];
    }
#pragma unroll 1
    for (int k = 0; k < KK; k++) {
        if (k + 1 < KK) {   // prefetch next gathered row while computing current
            int idxn = nidx[(k + 1) * NVOX + v];
            mn = get_mask(nmask, fl, (long)(k + 1) * NVOX + v);
            const float4* rn = (const float4*)(h1 + (size_t)idxn * 32);
#pragma unroll
            for (int q = 0; q < 8; q++) b[q] = rn[q];
        }
        const float* wk = Wh + k * 1024;
#pragma unroll
        for (int c = 0; c < 32; c++) {
            float4 aq = a[c >> 2];
            float rc = ((c & 3) == 0 ? aq.x : (c & 3) == 1 ? aq.y : (c & 3) == 2 ? aq.z : aq.w) * m;
            const float* wc = wk + c * 32;   // wave-uniform address -> s_load
#pragma unroll
            for (int d = 0; d < 16; d++) acc[d] = fmaf(rc, wc[d], acc[d]);
        }
#pragma unroll
        for (int q = 0; q < 8; q++) a[q] = b[q];
        m = mn;
    }
    const float* gp = g2 + half * 16;
    const float* bp = b2 + half * 16;
    float o[16];
#pragma unroll
    for (int d = 0; d < 16; d++) o[d] = fmaxf(acc[d] * gp[d] + bp[d], 0.f);
    float4* op = (float4*)(h2 + (size_t)v * 32 + half * 16);
#pragma unroll
    for (int q = 0; q < 4; q++)
        op[q] = make_float4(o[q * 4], o[q * 4 + 1], o[q * 4 + 2], o[q * 4 + 3]);
}

// ---- per-batch pooling: register accumulation, tiny atomic tail ----
__global__ __launch_bounds__(256) void k_pool(
        const float* __restrict__ h2, const int* __restrict__ vb,
        float* bsum, unsigned int* bmax, float* bcnt) {
    __shared__ float ls[NB * 32];
    __shared__ unsigned int lm[NB * 32];
    __shared__ float lc[NB];
    for (int i = threadIdx.x; i < NB * 32; i += 256) { ls[i] = 0.f; lm[i] = 0u; }
    if (threadIdx.x < NB) lc[threadIdx.x] = 0.f;
    __syncthreads();
    int c = threadIdx.x & 31, slot = threadIdx.x >> 5;
    float s0 = 0, s1 = 0, s2 = 0, s3 = 0, m0 = 0, m1 = 0, m2 = 0, m3 = 0;
    float c0 = 0, c1 = 0, c2 = 0, c3 = 0;
    for (int n = blockIdx.x * 8 + slot; n < NVOX; n += gridDim.x * 8) {
        float vv = h2[(size_t)n * 32 + c];
        int b = vb[n];
        s0 += (b == 0) ? vv : 0.f; m0 = (b == 0) ? fmaxf(m0, vv) : m0;
        s1 += (b == 1) ? vv : 0.f; m1 = (b == 1) ? fmaxf(m1, vv) : m1;
        s2 += (b == 2) ? vv : 0.f; m2 = (b == 2) ? fmaxf(m2, vv) : m2;
        s3 += (b == 3) ? vv : 0.f; m3 = (b == 3) ? fmaxf(m3, vv) : m3;
        if (c == 0) {
            c0 += (b == 0) ? 1.f : 0.f; c1 += (b == 1) ? 1.f : 0.f;
            c2 += (b == 2) ? 1.f : 0.f; c3 += (b == 3) ? 1.f : 0.f;
        }
    }
    atomicAdd(&ls[0 * 32 + c], s0); atomicAdd(&ls[1 * 32 + c], s1);
    atomicAdd(&ls[2 * 32 + c], s2); atomicAdd(&ls[3 * 32 + c], s3);
    atomicMax(&lm[0 * 32 + c], __float_as_uint(m0));  // h2 >= 0
    atomicMax(&lm[1 * 32 + c], __float_as_uint(m1));
    atomicMax(&lm[2 * 32 + c], __float_as_uint(m2));
    atomicMax(&lm[3 * 32 + c], __float_as_uint(m3));
    if (c == 0) {
        atomicAdd(&lc[0], c0); atomicAdd(&lc[1], c1);
        atomicAdd(&lc[2], c2); atomicAdd(&lc[3], c3);
    }
    __syncthreads();
    if (threadIdx.x < NB * 32) {
        atomicAdd(&bsum[threadIdx.x], ls[threadIdx.x]);
        atomicMax(&bmax[threadIdx.x], lm[threadIdx.x]);
    }
    if (threadIdx.x < NB) atomicAdd(&bcnt[threadIdx.x], lc[threadIdx.x]);
}

// ---- channel-attention MLP (tiny, 4 batches) ----
__global__ void k_ca(const float* __restrict__ bsum, const unsigned int* __restrict__ bmax,
                     const float* __restrict__ bcnt,
                     const float* __restrict__ w1, const float* __restrict__ b1,
                     const float* __restrict__ w2, const float* __restrict__ b2,
                     float* ca) {
    int b = threadIdx.x;
    if (b >= NB) return;
    float avg[32], mx[32], o[32];
    float inv = 1.0f / fmaxf(bcnt[b], 1.0f);
#pragma unroll
    for (int c = 0; c < 32; c++) {
        avg[c] = bsum[b * 32 + c] * inv;
        mx[c]  = __uint_as_float(bmax[b * 32 + c]);
        o[c] = 0.f;
    }
#pragma unroll
    for (int pass = 0; pass < 2; pass++) {
        float r[8];
#pragma unroll
        for (int j = 0; j < 8; j++) {
            float s = b1[j];
#pragma unroll
            for (int c = 0; c < 32; c++) s += (pass ? mx[c] : avg[c]) * w1[c * 8 + j];
            r[j] = fmaxf(s, 0.f);
        }
#pragma unroll
        for (int d = 0; d < 32; d++) {
            float s = b2[d];
#pragma unroll
            for (int j = 0; j < 8; j++) s += r[j] * w2[j * 32 + d];
            o[d] += s;
        }
    }
#pragma unroll
    for (int d = 0; d < 32; d++)
        ca[b * 32 + d] = 1.0f / (1.0f + expf(-o[d]));
}

// ---- apply channel attention (in place) + build s2 = [mean_c, max_c]; 2 thr/voxel ----
__global__ void k_apply(float* h2, const float* __restrict__ ca,
                        const int* __restrict__ vb, float* __restrict__ s2) {
    int t = blockIdx.x * 256 + threadIdx.x;
    int v = t >> 1, hf = t & 1;
    if (v >= NVOX) return;
    int b = vb[v];
    float4* hp = (float4*)(h2 + (size_t)v * 32) + hf * 4;
    const float4* cp = (const float4*)(ca + b * 32) + hf * 4;
    float sum = 0.f, mx = 0.f;
#pragma unroll
    for (int q = 0; q < 4; q++) {
        float4 h = hp[q]; float4 c = cp[q];
        h.x *= c.x; h.y *= c.y; h.z *= c.z; h.w *= c.w;
        hp[q] = h;
        sum += h.x + h.y + h.z + h.w;
        mx = fmaxf(mx, fmaxf(fmaxf(h.x, h.y), fmaxf(h.z, h.w)));
    }
    sum += __shfl_xor(sum, 1);
    mx = fmaxf(mx, __shfl_xor(mx, 1));
    if (hf == 0) {
        s2[v * 2 + 0] = sum * (1.0f / 32.0f);
        s2[v * 2 + 1] = mx;
    }
}

// ---- spatial attention: 2-ch sparse conv -> sigmoid; 4 thr/voxel, k-split ----
__global__ void k_saconv(const float* __restrict__ s2, const float* __restrict__ saW,
                         const int* __restrict__ nidx, const void* __restrict__ nmask,
                         const int* __restrict__ flag, float* __restrict__ sa) {
    __shared__ float w[KK * 2];
    if (threadIdx.x < KK * 2) w[threadIdx.x] = saW[threadIdx.x];
    __syncthreads();
    int t = blockIdx.x * 256 + threadIdx.x;
    int v = t >> 2, q = t & 3;
    if (v >= NVOX) return;
    int fl = *flag;
    float acc = 0.f;
    for (int k = q; k < KK; k += 4) {
        int idx = nidx[k * NVOX + v];
        float m = get_mask(nmask, fl, (long)k * NVOX + v);
        float2 s = ((const float2*)s2)[idx];
        acc += m * (s.x * w[k * 2] + s.y * w[k * 2 + 1]);
    }
    acc += __shfl_xor(acc, 1);
    acc += __shfl_xor(acc, 2);
    if (q == 0) sa[v] = 1.0f / (1.0f + expf(-acc));
}

// ---- gather to points, apply sa, classifier ----
__global__ __launch_bounds__(256) void k_final(
        const float* __restrict__ h2, const float* __restrict__ sa,
        const int* __restrict__ p2v, const float* __restrict__ clsw,
        const float* __restrict__ clsb, float* __restrict__ out) {
    __shared__ float w[32 * 20];
    __shared__ float bb[20];
    for (int i = threadIdx.x; i < 640; i += 256) w[i] = clsw[i];
    if (threadIdx.x < 20) bb[threadIdx.x] = clsb[threadIdx.x];
    __syncthreads();
    int p = blockIdx.x * 256 + threadIdx.x;
    if (p >= NPTS) return;
    int v = p2v[p];
    float s = sa[v];
    float acc[20];
#pragma unroll
    for (int j = 0; j < 20; j++) acc[j] = bb[j];
    const float4* hp = (const float4*)(h2 + (size_t)v * 32);
#pragma unroll
    for (int q = 0; q < 8; q++) {
        float4 h = hp[q];
        float z0 = h.x * s, z1 = h.y * s, z2 = h.z * s, z3 = h.w * s;
#pragma unroll
        for (int j = 0; j < 20; j++)
            acc[j] += z0 * w[(q * 4 + 0) * 20 + j] + z1 * w[(q * 4 + 1) * 20 + j]
                    + z2 * w[(q * 4 + 2) * 20 + j] + z3 * w[(q * 4 + 3) * 20 + j];
    }
#pragma unroll
    for (int j = 0; j < 20; j++) out[(long)p * 20 + j] = acc[j];
}

extern "C" void kernel_launch(void* const* d_in, const int* in_sizes, int n_in,
                              void* d_out, int out_size, void* d_ws, size_t ws_size,
                              hipStream_t stream) {
    const float* feat = (const float*)d_in[0];
    const float* W1   = (const float*)d_in[1];
    const float* g1   = (const float*)d_in[2];
    const float* b1   = (const float*)d_in[3];
    const float* W2   = (const float*)d_in[4];
    const float* g2   = (const float*)d_in[5];
    const float* b2   = (const float*)d_in[6];
    const float* caw1 = (const float*)d_in[7];
    const float* cab1 = (const float*)d_in[8];
    const float* caw2 = (const float*)d_in[9];
    const float* cab2 = (const float*)d_in[10];
    const float* saW  = (const float*)d_in[11];
    const float* clsw = (const float*)d_in[12];
    const float* clsb = (const float*)d_in[13];
    const int* p2v    = (const int*)d_in[14];
    const int* vb     = (const int*)d_in[15];
    const int* nidx   = (const int*)d_in[16];
    const void* nmask = d_in[17];
    float* out = (float*)d_out;

    float* f = (float*)d_ws;
    int* flag   = (int*)d_ws;
    float* cnt  = f + 64;                         // 60000
    float* vox  = cnt + NVOX;                     // 240000
    float* bsum = vox + (size_t)NVOX * 4;         // 128
    unsigned int* bmax = (unsigned int*)(bsum + NB * 32);  // 128
    float* bcnt = (float*)(bmax + NB * 32);       // 4
    float* ca   = bcnt + 64;                      // 128 (64-float pad for alignment)
    float* h1   = ca + 128;                       // 1.92M
    float* h2   = h1 + (size_t)NVOX * 32;
    float* s2   = h2 + (size_t)NVOX * 32;
    float* sa   = s2 + (size_t)NVOX * 2;

    // single memset covering cnt, vox, bsum, bmax, bcnt (contiguous)
    hipMemsetAsync(cnt, 0, (size_t)(NVOX * 5 + NB * 32 * 2 + NB) * sizeof(float), stream);
    k_detect<<<1, 256, 0, stream>>>((const unsigned int*)nmask, flag);
    k_scatter<<<(NPTS + 255) / 256, 256, 0, stream>>>((const float4*)feat, p2v, cnt, vox);
    k_voxdiv<<<(NVOX + 255) / 256, 256, 0, stream>>>(vox, cnt);
    k_conv1<<<(NVOX + 127) / 128, 256, 0, stream>>>(vox, W1, g1, b1, nidx, nmask, flag, h1);
    k_conv2<<<(NVOX + 127) / 128, 256, 0, stream>>>(h1, W2, g2, b2, nidx, nmask, flag, h2);
    k_pool<<<128, 256, 0, stream>>>(h2, vb, bsum, bmax, bcnt);
    k_ca<<<1, 64, 0, stream>>>(bsum, bmax, bcnt, caw1, cab1, caw2, cab2, ca);
    k_apply<<<(NVOX * 2 + 255) / 256, 256, 0, stream>>>(h2, ca, vb, s2);
    k_saconv<<<(NVOX * 4 + 255) / 256, 256, 0, stream>>>(s2, saW, nidx, nmask, flag, sa);
    k_final<<<(NPTS + 255) / 256, 256, 0, stream>>>(h2, sa, p2v, clsw, clsb, out);
}

// Round 3
// 240.544 us; speedup vs baseline: 1.1542x; 1.1188x over previous
//
#include <hip/hip_runtime.h>
#include <hip/hip_bf16.h>

#define NPTS 200000
#define NVOX 60000
#define NB 4
#define KK 27

// ---- mask encoding: 0 = uint8 bool, 1 = int32, 2 = float32 ----
__device__ __forceinline__ float get_mask(const void* nm, int fl, long i) {
    if (fl == 0) return ((const unsigned char*)nm)[i] ? 1.0f : 0.0f;
    if (fl == 1) return ((const int*)nm)[i] ? 1.0f : 0.0f;
    return ((const float*)nm)[i];
}

__global__ void k_detect(const unsigned int* nm, int* flag) {
    __shared__ int cntF, cntI;
    if (threadIdx.x == 0) { cntF = 0; cntI = 0; }
    __syncthreads();
    int f = 0, i1 = 0;
    for (int i = threadIdx.x; i < 1024; i += 256) {
        unsigned int v = nm[i];
        if (v == 0x3f800000u) f++;
        if (v == 1u) i1++;
    }
    atomicAdd(&cntF, f); atomicAdd(&cntI, i1);
    __syncthreads();
    if (threadIdx.x == 0)
        *flag = (cntF > 100) ? 2 : ((cntI > 100) ? 1 : 0);
}

// ---- voxelize: scatter-add points into voxels (raw sums; divide fused into conv1) ----
__global__ void k_scatter(const float4* __restrict__ feat, const int* __restrict__ p2v,
                          float* cnt, float* vox) {
    int p = blockIdx.x * 256 + threadIdx.x;
    if (p >= NPTS) return;
    int v = p2v[p];
    float4 f = feat[p];
    atomicAdd(&cnt[v], 1.0f);
    atomicAdd(&vox[v * 4 + 0], f.x);
    atomicAdd(&vox[v * 4 + 1], f.y);
    atomicAdd(&vox[v * 4 + 2], f.z);
    atomicAdd(&vox[v * 4 + 3], f.w);
}

// ---- conv1: Cin=4 -> Cout=32; thread = (voxel, quad of 8 out-ch); voxdiv fused ----
__global__ __launch_bounds__(256) void k_conv1(
        const float* __restrict__ vox, const float* __restrict__ cnt,
        const float* __restrict__ W1,
        const float* __restrict__ g1, const float* __restrict__ b1,
        const int* __restrict__ nidx, const void* __restrict__ nmask,
        const int* __restrict__ flag, float* __restrict__ h1) {
    int tid = threadIdx.x;
    int vl = tid & 63;
    int q = __builtin_amdgcn_readfirstlane(tid >> 6);   // wave-uniform quad
    int v = blockIdx.x * 64 + vl;
    int vc = v < NVOX ? v : NVOX - 1;
    int fl = *flag;
    float acc[8];
#pragma unroll
    for (int d = 0; d < 8; d++) acc[d] = 0.f;
#pragma unroll 1
    for (int k = 0; k < KK; k++) {
        int idx = nidx[k * NVOX + vc];
        float m = get_mask(nmask, fl, (long)k * NVOX + vc);
        if (m != 0.f) {
            float4 r = ((const float4*)vox)[idx];
            float mm = m / fmaxf(cnt[idx], 1.0f);       // fused voxel average
            const float* wk = W1 + k * 128 + q * 8;     // wave-uniform -> s_load
#pragma unroll
            for (int c = 0; c < 4; c++) {
                float rc = (c == 0 ? r.x : c == 1 ? r.y : c == 2 ? r.z : r.w) * mm;
#pragma unroll
                for (int d = 0; d < 8; d++) acc[d] = fmaf(rc, wk[c * 32 + d], acc[d]);
            }
        }
    }
    if (v < NVOX) {
        const float* gp = g1 + q * 8;
        const float* bp = b1 + q * 8;
        float o[8];
#pragma unroll
        for (int d = 0; d < 8; d++) o[d] = fmaxf(acc[d] * gp[d] + bp[d], 0.f);
        float4* op = (float4*)(h1 + (size_t)v * 32 + q * 8);
        op[0] = make_float4(o[0], o[1], o[2], o[3]);
        op[1] = make_float4(o[4], o[5], o[6], o[7]);
    }
}

// ---- conv2: Cin=32 -> Cout=32; 512 thr = 64 vox x 2 halves x 4 k-chunks ----
__global__ __launch_bounds__(512) void k_conv2(
        const float* __restrict__ h1, const float* __restrict__ W2,
        const float* __restrict__ g2, const float* __restrict__ b2,
        const int* __restrict__ nidx, const void* __restrict__ nmask,
        const int* __restrict__ flag, float* __restrict__ h2) {
    __shared__ float part[3][64][33];   // stride 33: 2-way max on combine (free)
    int tid = threadIdx.x;
    int vl = tid & 63;
    int half = __builtin_amdgcn_readfirstlane((tid >> 6) & 1);  // wave-uniform
    int kc   = __builtin_amdgcn_readfirstlane(tid >> 7);        // wave-uniform
    int v = blockIdx.x * 64 + vl;
    int vc = v < NVOX ? v : NVOX - 1;
    int fl = *flag;
    int k0 = kc * 7;
    int k1 = (k0 + 7 < KK) ? k0 + 7 : KK;   // chunks 7,7,7,6
    const float* Wh = W2 + half * 16;
    float acc[16];
#pragma unroll
    for (int d = 0; d < 16; d++) acc[d] = 0.f;
#pragma unroll 1
    for (int k = k0; k < k1; k++) {
        int idx = nidx[k * NVOX + vc];
        float m = get_mask(nmask, fl, (long)k * NVOX + vc);
        if (m != 0.f) {                      // exec-masked: skips gather for masked lanes
            float4 a[8];
            const float4* rp = (const float4*)(h1 + (size_t)idx * 32);
#pragma unroll
            for (int qq = 0; qq < 8; qq++) a[qq] = rp[qq];
            const float* wk = Wh + k * 1024;  // wave-uniform -> s_load
#pragma unroll
            for (int c = 0; c < 32; c++) {
                float4 aq = a[c >> 2];
                float rc = ((c & 3) == 0 ? aq.x : (c & 3) == 1 ? aq.y :
                            (c & 3) == 2 ? aq.z : aq.w) * m;
                const float* wc = wk + c * 32;
#pragma unroll
                for (int d = 0; d < 16; d++) acc[d] = fmaf(rc, wc[d], acc[d]);
            }
        }
    }
    if (kc > 0) {
#pragma unroll
        for (int d = 0; d < 16; d++) part[kc - 1][vl][half * 16 + d] = acc[d];
    }
    __syncthreads();
    if (kc == 0 && v < NVOX) {
#pragma unroll
        for (int d = 0; d < 16; d++)
            acc[d] += part[0][vl][half * 16 + d] + part[1][vl][half * 16 + d]
                    + part[2][vl][half * 16 + d];
        const float* gp = g2 + half * 16;
        const float* bp = b2 + half * 16;
        float o[16];
#pragma unroll
        for (int d = 0; d < 16; d++) o[d] = fmaxf(acc[d] * gp[d] + bp[d], 0.f);
        float4* op = (float4*)(h2 + (size_t)v * 32 + half * 16);
#pragma unroll
        for (int qq = 0; qq < 4; qq++)
            op[qq] = make_float4(o[qq * 4], o[qq * 4 + 1], o[qq * 4 + 2], o[qq * 4 + 3]);
    }
}

// ---- per-batch pooling: register accumulation, tiny atomic tail ----
__global__ __launch_bounds__(256) void k_pool(
        const float* __restrict__ h2, const int* __restrict__ vb,
        float* bsum, unsigned int* bmax, float* bcnt) {
    __shared__ float ls[NB * 32];
    __shared__ unsigned int lm[NB * 32];
    __shared__ float lc[NB];
    for (int i = threadIdx.x; i < NB * 32; i += 256) { ls[i] = 0.f; lm[i] = 0u; }
    if (threadIdx.x < NB) lc[threadIdx.x] = 0.f;
    __syncthreads();
    int c = threadIdx.x & 31, slot = threadIdx.x >> 5;
    float s0 = 0, s1 = 0, s2 = 0, s3 = 0, m0 = 0, m1 = 0, m2 = 0, m3 = 0;
    float c0 = 0, c1 = 0, c2 = 0, c3 = 0;
    for (int n = blockIdx.x * 8 + slot; n < NVOX; n += gridDim.x * 8) {
        float vv = h2[(size_t)n * 32 + c];
        int b = vb[n];
        s0 += (b == 0) ? vv : 0.f; m0 = (b == 0) ? fmaxf(m0, vv) : m0;
        s1 += (b == 1) ? vv : 0.f; m1 = (b == 1) ? fmaxf(m1, vv) : m1;
        s2 += (b == 2) ? vv : 0.f; m2 = (b == 2) ? fmaxf(m2, vv) : m2;
        s3 += (b == 3) ? vv : 0.f; m3 = (b == 3) ? fmaxf(m3, vv) : m3;
        if (c == 0) {
            c0 += (b == 0) ? 1.f : 0.f; c1 += (b == 1) ? 1.f : 0.f;
            c2 += (b == 2) ? 1.f : 0.f; c3 += (b == 3) ? 1.f : 0.f;
        }
    }
    atomicAdd(&ls[0 * 32 + c], s0); atomicAdd(&ls[1 * 32 + c], s1);
    atomicAdd(&ls[2 * 32 + c], s2); atomicAdd(&ls[3 * 32 + c], s3);
    atomicMax(&lm[0 * 32 + c], __float_as_uint(m0));  // h2 >= 0
    atomicMax(&lm[1 * 32 + c], __float_as_uint(m1));
    atomicMax(&lm[2 * 32 + c], __float_as_uint(m2));
    atomicMax(&lm[3 * 32 + c], __float_as_uint(m3));
    if (c == 0) {
        atomicAdd(&lc[0], c0); atomicAdd(&lc[1], c1);
        atomicAdd(&lc[2], c2); atomicAdd(&lc[3], c3);
    }
    __syncthreads();
    if (threadIdx.x < NB * 32) {
        atomicAdd(&bsum[threadIdx.x], ls[threadIdx.x]);
        atomicMax(&bmax[threadIdx.x], lm[threadIdx.x]);
    }
    if (threadIdx.x < NB) atomicAdd(&bcnt[threadIdx.x], lc[threadIdx.x]);
}

// ---- channel-attention MLP (tiny, 4 batches) ----
__global__ void k_ca(const float* __restrict__ bsum, const unsigned int* __restrict__ bmax,
                     const float* __restrict__ bcnt,
                     const float* __restrict__ w1, const float* __restrict__ b1,
                     const float* __restrict__ w2, const float* __restrict__ b2,
                     float* ca) {
    int b = threadIdx.x;
    if (b >= NB) return;
    float avg[32], mx[32], o[32];
    float inv = 1.0f / fmaxf(bcnt[b], 1.0f);
#pragma unroll
    for (int c = 0; c < 32; c++) {
        avg[c] = bsum[b * 32 + c] * inv;
        mx[c]  = __uint_as_float(bmax[b * 32 + c]);
        o[c] = 0.f;
    }
#pragma unroll
    for (int pass = 0; pass < 2; pass++) {
        float r[8];
#pragma unroll
        for (int j = 0; j < 8; j++) {
            float s = b1[j];
#pragma unroll
            for (int c = 0; c < 32; c++) s += (pass ? mx[c] : avg[c]) * w1[c * 8 + j];
            r[j] = fmaxf(s, 0.f);
        }
#pragma unroll
        for (int d = 0; d < 32; d++) {
            float s = b2[d];
#pragma unroll
            for (int j = 0; j < 8; j++) s += r[j] * w2[j * 32 + d];
            o[d] += s;
        }
    }
#pragma unroll
    for (int d = 0; d < 32; d++)
        ca[b * 32 + d] = 1.0f / (1.0f + expf(-o[d]));
}

// ---- apply channel attention (in place) + build s2 = [mean_c, max_c]; 2 thr/voxel ----
__global__ void k_apply(float* h2, const float* __restrict__ ca,
                        const int* __restrict__ vb, float* __restrict__ s2) {
    int t = blockIdx.x * 256 + threadIdx.x;
    int v = t >> 1, hf = t & 1;
    if (v >= NVOX) return;
    int b = vb[v];
    float4* hp = (float4*)(h2 + (size_t)v * 32) + hf * 4;
    const float4* cp = (const float4*)(ca + b * 32) + hf * 4;
    float sum = 0.f, mx = 0.f;
#pragma unroll
    for (int q = 0; q < 4; q++) {
        float4 h = hp[q]; float4 c = cp[q];
        h.x *= c.x; h.y *= c.y; h.z *= c.z; h.w *= c.w;
        hp[q] = h;
        sum += h.x + h.y + h.z + h.w;
        mx = fmaxf(mx, fmaxf(fmaxf(h.x, h.y), fmaxf(h.z, h.w)));
    }
    sum += __shfl_xor(sum, 1);
    mx = fmaxf(mx, __shfl_xor(mx, 1));
    if (hf == 0) {
        s2[v * 2 + 0] = sum * (1.0f / 32.0f);
        s2[v * 2 + 1] = mx;
    }
}

// ---- spatial attention: 2-ch sparse conv -> sigmoid; 4 thr/voxel, k-split ----
__global__ void k_saconv(const float* __restrict__ s2, const float* __restrict__ saW,
                         const int* __restrict__ nidx, const void* __restrict__ nmask,
                         const int* __restrict__ flag, float* __restrict__ sa) {
    __shared__ float w[KK * 2];
    if (threadIdx.x < KK * 2) w[threadIdx.x] = saW[threadIdx.x];
    __syncthreads();
    int t = blockIdx.x * 256 + threadIdx.x;
    int v = t >> 2, q = t & 3;
    if (v >= NVOX) return;
    int fl = *flag;
    float acc = 0.f;
    for (int k = q; k < KK; k += 4) {
        int idx = nidx[k * NVOX + v];
        float m = get_mask(nmask, fl, (long)k * NVOX + v);
        float2 s = ((const float2*)s2)[idx];
        acc += m * (s.x * w[k * 2] + s.y * w[k * 2 + 1]);
    }
    acc += __shfl_xor(acc, 1);
    acc += __shfl_xor(acc, 2);
    if (q == 0) sa[v] = 1.0f / (1.0f + expf(-acc));
}

// ---- gather to points, apply sa, classifier ----
__global__ __launch_bounds__(256) void k_final(
        const float* __restrict__ h2, const float* __restrict__ sa,
        const int* __restrict__ p2v, const float* __restrict__ clsw,
        const float* __restrict__ clsb, float* __restrict__ out) {
    __shared__ float w[32 * 20];
    __shared__ float bb[20];
    for (int i = threadIdx.x; i < 640; i += 256) w[i] = clsw[i];
    if (threadIdx.x < 20) bb[threadIdx.x] = clsb[threadIdx.x];
    __syncthreads();
    int p = blockIdx.x * 256 + threadIdx.x;
    if (p >= NPTS) return;
    int v = p2v[p];
    float s = sa[v];
    float acc[20];
#pragma unroll
    for (int j = 0; j < 20; j++) acc[j] = bb[j];
    const float4* hp = (const float4*)(h2 + (size_t)v * 32);
#pragma unroll
    for (int q = 0; q < 8; q++) {
        float4 h = hp[q];
        float z0 = h.x * s, z1 = h.y * s, z2 = h.z * s, z3 = h.w * s;
#pragma unroll
        for (int j = 0; j < 20; j++)
            acc[j] += z0 * w[(q * 4 + 0) * 20 + j] + z1 * w[(q * 4 + 1) * 20 + j]
                    + z2 * w[(q * 4 + 2) * 20 + j] + z3 * w[(q * 4 + 3) * 20 + j];
    }
#pragma unroll
    for (int j = 0; j < 20; j++) out[(long)p * 20 + j] = acc[j];
}

extern "C" void kernel_launch(void* const* d_in, const int* in_sizes, int n_in,
                              void* d_out, int out_size, void* d_ws, size_t ws_size,
                              hipStream_t stream) {
    const float* feat = (const float*)d_in[0];
    const float* W1   = (const float*)d_in[1];
    const float* g1   = (const float*)d_in[2];
    const float* b1   = (const float*)d_in[3];
    const float* W2   = (const float*)d_in[4];
    const float* g2   = (const float*)d_in[5];
    const float* b2   = (const float*)d_in[6];
    const float* caw1 = (const float*)d_in[7];
    const float* cab1 = (const float*)d_in[8];
    const float* caw2 = (const float*)d_in[9];
    const float* cab2 = (const float*)d_in[10];
    const float* saW  = (const float*)d_in[11];
    const float* clsw = (const float*)d_in[12];
    const float* clsb = (const float*)d_in[13];
    const int* p2v    = (const int*)d_in[14];
    const int* vb     = (const int*)d_in[15];
    const int* nidx   = (const int*)d_in[16];
    const void* nmask = d_in[17];
    float* out = (float*)d_out;

    float* f = (float*)d_ws;
    int* flag   = (int*)d_ws;
    float* cnt  = f + 64;                         // 60000
    float* vox  = cnt + NVOX;                     // 240000 (raw sums)
    float* bsum = vox + (size_t)NVOX * 4;         // 128
    unsigned int* bmax = (unsigned int*)(bsum + NB * 32);  // 128
    float* bcnt = (float*)(bmax + NB * 32);       // 4
    float* ca   = bcnt + 64;                      // 128 (padded)
    float* h1   = ca + 128;
    float* h2   = h1 + (size_t)NVOX * 32;
    float* s2   = h2 + (size_t)NVOX * 32;
    float* sa   = s2 + (size_t)NVOX * 2;

    hipMemsetAsync(cnt, 0, (size_t)(NVOX * 5 + NB * 32 * 2 + NB) * sizeof(float), stream);
    k_detect<<<1, 256, 0, stream>>>((const unsigned int*)nmask, flag);
    k_scatter<<<(NPTS + 255) / 256, 256, 0, stream>>>((const float4*)feat, p2v, cnt, vox);
    k_conv1<<<(NVOX + 63) / 64, 256, 0, stream>>>(vox, cnt, W1, g1, b1, nidx, nmask, flag, h1);
    k_conv2<<<(NVOX + 63) / 64, 512, 0, stream>>>(h1, W2, g2, b2, nidx, nmask, flag, h2);
    k_pool<<<512, 256, 0, stream>>>(h2, vb, bsum, bmax, bcnt);
    k_ca<<<1, 64, 0, stream>>>(bsum, bmax, bcnt, caw1, cab1, caw2, cab2, ca);
    k_apply<<<(NVOX * 2 + 255) / 256, 256, 0, stream>>>(h2, ca, vb, s2);
    k_saconv<<<(NVOX * 4 + 255) / 256, 256, 0, stream>>>(s2, saW, nidx, nmask, flag, sa);
    k_final<<<(NPTS + 255) / 256, 256, 0, stream>>>(h2, sa, p2v, clsw, clsb, out);
}